// Round 1
// baseline (1794.896 us; speedup 1.0000x reference)
//
#include <hip/hip_runtime.h>
#include <math.h>

#define NN 50000
#define NE 800000
#define F_IN 64
#define HID 128
#define HEADS 4
#define LAYERS 3

// ---------------- CSR build ----------------

__global__ void hist_kernel(const int* __restrict__ dst, int* __restrict__ counts, int E) {
  int e = blockIdx.x * blockDim.x + threadIdx.x;
  if (e < E) atomicAdd(&counts[dst[e]], 1);
}

__global__ void scan_kernel(const int* __restrict__ counts, int* __restrict__ indptr, int n) {
  __shared__ int buf[1024];
  __shared__ int carry_s;
  int tid = threadIdx.x;
  if (tid == 0) carry_s = 0;
  __syncthreads();
  for (int base = 0; base < n; base += 1024) {
    int v = (base + tid < n) ? counts[base + tid] : 0;
    buf[tid] = v;
    __syncthreads();
    for (int off = 1; off < 1024; off <<= 1) {
      int t = (tid >= off) ? buf[tid - off] : 0;
      __syncthreads();
      buf[tid] += t;
      __syncthreads();
    }
    int incl = buf[tid];
    int total = buf[1023];
    int carry = carry_s;
    if (base + tid < n) indptr[base + tid] = carry + incl - v;
    __syncthreads();
    if (tid == 0) carry_s = carry + total;
    __syncthreads();
  }
  if (tid == 0) indptr[n] = carry_s;
}

__global__ void scatter_kernel(const int* __restrict__ src, const int* __restrict__ dst,
                               const int* __restrict__ indptr, int* __restrict__ fill,
                               int* __restrict__ srcs, int E) {
  int e = blockIdx.x * blockDim.x + threadIdx.x;
  if (e < E) {
    int d = dst[e];
    int pos = atomicAdd(&fill[d], 1);
    srcs[indptr[d] + pos] = src[e];
  }
}

// ---------------- fp32 tiled GEMM: C = act(A[M,K] @ B[K,Nc] + bias) ----------------
// 64x64 tile, 256 threads, 4x4 per thread, BK=16. Nc % 64 == 0, K % 16 == 0.

template <int ACT>
__global__ void __launch_bounds__(256)
gemm_bias(const float* __restrict__ A, const float* __restrict__ B,
          const float* __restrict__ bias, float* __restrict__ C,
          int M, int K, int Nc) {
  __shared__ float As[16][68];  // transposed A tile: As[k][m]
  __shared__ float Bs[16][68];
  int tid = threadIdx.x;
  int tx = tid & 15, ty = tid >> 4;
  int m0 = blockIdx.y * 64;
  int n0 = blockIdx.x * 64;

  int arow = tid >> 2;        // 0..63
  int acol = (tid & 3) * 4;   // 0,4,8,12
  int brow = tid >> 4;        // 0..15
  int bcol = (tid & 15) * 4;  // 0..60

  float acc[4][4];
#pragma unroll
  for (int i = 0; i < 4; ++i)
#pragma unroll
    for (int j = 0; j < 4; ++j) acc[i][j] = 0.f;

  for (int k0 = 0; k0 < K; k0 += 16) {
    float4 av = make_float4(0.f, 0.f, 0.f, 0.f);
    if (m0 + arow < M) av = *(const float4*)&A[(size_t)(m0 + arow) * K + k0 + acol];
    As[acol + 0][arow] = av.x;
    As[acol + 1][arow] = av.y;
    As[acol + 2][arow] = av.z;
    As[acol + 3][arow] = av.w;
    float4 bv = *(const float4*)&B[(size_t)(k0 + brow) * Nc + n0 + bcol];
    *(float4*)&Bs[brow][bcol] = bv;
    __syncthreads();
#pragma unroll
    for (int k = 0; k < 16; ++k) {
      float4 a = *(const float4*)&As[k][ty * 4];
      float4 b = *(const float4*)&Bs[k][tx * 4];
      acc[0][0] += a.x * b.x; acc[0][1] += a.x * b.y; acc[0][2] += a.x * b.z; acc[0][3] += a.x * b.w;
      acc[1][0] += a.y * b.x; acc[1][1] += a.y * b.y; acc[1][2] += a.y * b.z; acc[1][3] += a.y * b.w;
      acc[2][0] += a.z * b.x; acc[2][1] += a.z * b.y; acc[2][2] += a.z * b.z; acc[2][3] += a.z * b.w;
      acc[3][0] += a.w * b.x; acc[3][1] += a.w * b.y; acc[3][2] += a.w * b.z; acc[3][3] += a.w * b.w;
    }
    __syncthreads();
  }

#pragma unroll
  for (int i = 0; i < 4; ++i) {
    int row = m0 + ty * 4 + i;
    if (row < M) {
#pragma unroll
      for (int j = 0; j < 4; ++j) {
        int col = n0 + tx * 4 + j;
        float v = acc[i][j] + bias[col];
        if (ACT) v = fmaxf(v, 0.f);
        C[(size_t)row * Nc + col] = v;
      }
    }
  }
}

// ---------------- GATv2 edge phase: online softmax + aggregate, 1 block per dst node ----------------
// xl, xr: [N, 4, 128]. 4 waves per block, wave = head, lane owns 2 channels.

__global__ void __launch_bounds__(256)
gat_aggregate(const float* __restrict__ xl, const float* __restrict__ xr,
              const int* __restrict__ indptr, const int* __restrict__ srcs,
              const float* __restrict__ att, const float* __restrict__ conv_bias,
              const float* __restrict__ h_in, float* __restrict__ h_out) {
  int n = blockIdx.x;
  int wave = threadIdx.x >> 6;
  int lane = threadIdx.x & 63;
  int c2 = lane * 2;

  float2 xrv = *(const float2*)(xr + (size_t)n * 512 + wave * 128 + c2);
  float2 attv = *(const float2*)(att + wave * 128 + c2);

  int beg = indptr[n];
  int end = indptr[n + 1];

  float m_run = -__builtin_inff();
  float s_run = 0.f;
  float ax = 0.f, ay = 0.f;

  for (int e = beg; e < end; ++e) {
    int s = srcs[e];
    float2 xlv = *(const float2*)(xl + (size_t)s * 512 + wave * 128 + c2);
    float mx = xlv.x + xrv.x;
    float my = xlv.y + xrv.y;
    float lx = mx > 0.f ? mx : 0.2f * mx;
    float ly = my > 0.f ? my : 0.2f * my;
    float p = attv.x * lx + attv.y * ly;
#pragma unroll
    for (int off = 32; off > 0; off >>= 1) p += __shfl_xor(p, off);
    float mn = fmaxf(m_run, p);
    float sc = expf(m_run - mn);   // exp(-inf) = 0 on first edge
    float w = expf(p - mn);
    s_run = s_run * sc + w;
    ax = ax * sc + w * xlv.x;
    ay = ay * sc + w * xlv.y;
    m_run = mn;
  }

  float inv = 1.f / fmaxf(s_run, 1e-16f);
  __shared__ float red[4][128];
  red[wave][c2] = ax * inv;
  red[wave][c2 + 1] = ay * inv;
  __syncthreads();

  if (threadIdx.x < 128) {
    int c = threadIdx.x;
    float v = (red[0][c] + red[1][c] + red[2][c] + red[3][c]) * 0.25f + conv_bias[c] +
              h_in[(size_t)n * 128 + c];
    h_out[(size_t)n * 128 + c] = fmaxf(v, 0.f);
  }
}

// ---------------- final: score = clip(z2 @ p3_W + p3_b) ----------------

__global__ void __launch_bounds__(256)
predictor_final(const float* __restrict__ z2, const float* __restrict__ w3,
                const float* __restrict__ b3, float* __restrict__ out, int n) {
  int node = (blockIdx.x << 2) + (threadIdx.x >> 6);
  int lane = threadIdx.x & 63;
  if (node >= n) return;
  float v = z2[(size_t)node * 64 + lane] * w3[lane];
#pragma unroll
  for (int off = 32; off > 0; off >>= 1) v += __shfl_xor(v, off);
  if (lane == 0) {
    float s = v + b3[0];
    s = fminf(fmaxf(s, -15.f), 15.f);
    out[node] = s;
  }
}

// ---------------- launch ----------------

extern "C" void kernel_launch(void* const* d_in, const int* in_sizes, int n_in,
                              void* d_out, int out_size, void* d_ws, size_t ws_size,
                              hipStream_t stream) {
  const float* x     = (const float*)d_in[0];
  const int*   ei    = (const int*)d_in[1];
  const float* emb_W = (const float*)d_in[3];
  const float* emb_b = (const float*)d_in[4];
  const float* Wl    = (const float*)d_in[5];
  const float* bl    = (const float*)d_in[6];
  const float* Wr    = (const float*)d_in[7];
  const float* br    = (const float*)d_in[8];
  const float* att   = (const float*)d_in[9];
  const float* cbias = (const float*)d_in[10];
  const float* p1W   = (const float*)d_in[11];
  const float* p1b   = (const float*)d_in[12];
  const float* p2W   = (const float*)d_in[13];
  const float* p2b   = (const float*)d_in[14];
  const float* p3W   = (const float*)d_in[15];
  const float* p3b   = (const float*)d_in[16];
  float* out = (float*)d_out;

  char* ws = (char*)d_ws;
  size_t o = 0;
  float* h0 = (float*)(ws + o); o += (size_t)NN * 128 * 4;            // 25.6 MB
  float* h1 = (float*)(ws + o); o += (size_t)NN * 128 * 4;            // 25.6 MB
  float* xl = (float*)(ws + o); o += (size_t)NN * 512 * 4;            // 102.4 MB
  float* xr = (float*)(ws + o); o += (size_t)NN * 512 * 4;            // 102.4 MB
  int* indptr = (int*)(ws + o); o += (((size_t)(NN + 1) * 4) + 255) / 256 * 256;
  int* counts = (int*)(ws + o); o += (((size_t)NN * 4) + 255) / 256 * 256;
  int* srcs   = (int*)(ws + o); o += (size_t)NE * 4;

  const int* esrc = ei;
  const int* edst = ei + NE;

  // Build dst-CSR (same for all layers)
  hipMemsetAsync(counts, 0, (size_t)NN * 4, stream);
  hist_kernel<<<(NE + 255) / 256, 256, 0, stream>>>(edst, counts, NE);
  scan_kernel<<<1, 1024, 0, stream>>>(counts, indptr, NN);
  hipMemsetAsync(counts, 0, (size_t)NN * 4, stream);
  scatter_kernel<<<(NE + 255) / 256, 256, 0, stream>>>(esrc, edst, indptr, counts, srcs, NE);

  // Embedding: h0 = relu(x @ emb_W + emb_b)
  gemm_bias<1><<<dim3(128 / 64, (NN + 63) / 64), 256, 0, stream>>>(x, emb_W, emb_b, h0, NN, 64, 128);

  float* hc = h0;
  float* hn = h1;
  for (int l = 0; l < LAYERS; ++l) {
    gemm_bias<0><<<dim3(512 / 64, (NN + 63) / 64), 256, 0, stream>>>(
        hc, Wl + (size_t)l * 128 * 512, bl + (size_t)l * 512, xl, NN, 128, 512);
    gemm_bias<0><<<dim3(512 / 64, (NN + 63) / 64), 256, 0, stream>>>(
        hc, Wr + (size_t)l * 128 * 512, br + (size_t)l * 512, xr, NN, 128, 512);
    gat_aggregate<<<NN, 256, 0, stream>>>(xl, xr, indptr, srcs,
                                          att + (size_t)l * 512, cbias + (size_t)l * 128, hc, hn);
    float* t = hc; hc = hn; hn = t;
  }

  // Predictor MLP (reuse xl/xr as z1/z2)
  float* z1 = xl;
  float* z2 = xr;
  gemm_bias<1><<<dim3(128 / 64, (NN + 63) / 64), 256, 0, stream>>>(hc, p1W, p1b, z1, NN, 128, 128);
  gemm_bias<1><<<dim3(64 / 64, (NN + 63) / 64), 256, 0, stream>>>(z1, p2W, p2b, z2, NN, 128, 64);
  predictor_final<<<(NN + 3) / 4, 256, 0, stream>>>(z2, p3W, p3b, out, NN);
}

// Round 2
// 1544.778 us; speedup vs baseline: 1.1619x; 1.1619x over previous
//
#include <hip/hip_runtime.h>
#include <math.h>

#define NN 50000
#define NE 800000
#define F_IN 64
#define HID 128
#define HEADS 4
#define LAYERS 3

// ---------------- CSR build ----------------

__global__ void hist_kernel(const int* __restrict__ dst, int* __restrict__ counts, int E) {
  int e = blockIdx.x * blockDim.x + threadIdx.x;
  if (e < E) atomicAdd(&counts[dst[e]], 1);
}

__global__ void scan_kernel(const int* __restrict__ counts, int* __restrict__ indptr, int n) {
  __shared__ int buf[1024];
  __shared__ int carry_s;
  int tid = threadIdx.x;
  if (tid == 0) carry_s = 0;
  __syncthreads();
  for (int base = 0; base < n; base += 1024) {
    int v = (base + tid < n) ? counts[base + tid] : 0;
    buf[tid] = v;
    __syncthreads();
    for (int off = 1; off < 1024; off <<= 1) {
      int t = (tid >= off) ? buf[tid - off] : 0;
      __syncthreads();
      buf[tid] += t;
      __syncthreads();
    }
    int incl = buf[tid];
    int total = buf[1023];
    int carry = carry_s;
    if (base + tid < n) indptr[base + tid] = carry + incl - v;
    __syncthreads();
    if (tid == 0) carry_s = carry + total;
    __syncthreads();
  }
  if (tid == 0) indptr[n] = carry_s;
}

__global__ void scatter_kernel(const int* __restrict__ src, const int* __restrict__ dst,
                               const int* __restrict__ indptr, int* __restrict__ fill,
                               int* __restrict__ srcs, int E) {
  int e = blockIdx.x * blockDim.x + threadIdx.x;
  if (e < E) {
    int d = dst[e];
    int pos = atomicAdd(&fill[d], 1);
    srcs[indptr[d] + pos] = src[e];
  }
}

// ---------------- fp32 tiled GEMM: C = act(A[M,K] @ B[K,Nc] + bias) ----------------

template <int ACT>
__global__ void __launch_bounds__(256)
gemm_bias(const float* __restrict__ A, const float* __restrict__ B,
          const float* __restrict__ bias, float* __restrict__ C,
          int M, int K, int Nc) {
  __shared__ float As[16][68];  // transposed A tile: As[k][m]
  __shared__ float Bs[16][68];
  int tid = threadIdx.x;
  int tx = tid & 15, ty = tid >> 4;
  int m0 = blockIdx.y * 64;
  int n0 = blockIdx.x * 64;

  int arow = tid >> 2;
  int acol = (tid & 3) * 4;
  int brow = tid >> 4;
  int bcol = (tid & 15) * 4;

  float acc[4][4];
#pragma unroll
  for (int i = 0; i < 4; ++i)
#pragma unroll
    for (int j = 0; j < 4; ++j) acc[i][j] = 0.f;

  for (int k0 = 0; k0 < K; k0 += 16) {
    float4 av = make_float4(0.f, 0.f, 0.f, 0.f);
    if (m0 + arow < M) av = *(const float4*)&A[(size_t)(m0 + arow) * K + k0 + acol];
    As[acol + 0][arow] = av.x;
    As[acol + 1][arow] = av.y;
    As[acol + 2][arow] = av.z;
    As[acol + 3][arow] = av.w;
    float4 bv = *(const float4*)&B[(size_t)(k0 + brow) * Nc + n0 + bcol];
    *(float4*)&Bs[brow][bcol] = bv;
    __syncthreads();
#pragma unroll
    for (int k = 0; k < 16; ++k) {
      float4 a = *(const float4*)&As[k][ty * 4];
      float4 b = *(const float4*)&Bs[k][tx * 4];
      acc[0][0] += a.x * b.x; acc[0][1] += a.x * b.y; acc[0][2] += a.x * b.z; acc[0][3] += a.x * b.w;
      acc[1][0] += a.y * b.x; acc[1][1] += a.y * b.y; acc[1][2] += a.y * b.z; acc[1][3] += a.y * b.w;
      acc[2][0] += a.z * b.x; acc[2][1] += a.z * b.y; acc[2][2] += a.z * b.z; acc[2][3] += a.z * b.w;
      acc[3][0] += a.w * b.x; acc[3][1] += a.w * b.y; acc[3][2] += a.w * b.z; acc[3][3] += a.w * b.w;
    }
    __syncthreads();
  }

#pragma unroll
  for (int i = 0; i < 4; ++i) {
    int row = m0 + ty * 4 + i;
    if (row < M) {
#pragma unroll
      for (int j = 0; j < 4; ++j) {
        int col = n0 + tx * 4 + j;
        float v = acc[i][j] + bias[col];
        if (ACT) v = fmaxf(v, 0.f);
        C[(size_t)row * Nc + col] = v;
      }
    }
  }
}

// ---------------- GATv2 edge phase, chunked: 1 block per dst node ----------------
// Score layout: lane = h*16+g, lane owns 8 channels ch = h*128+g*8.
// Each wave handles 2 edge slots per chunk of 8; softmax bookkeeping dense on wave 0;
// aggregation done in-register in score layout; cross-wave reduce at the end.

__global__ void __launch_bounds__(256)
gat_aggregate(const float* __restrict__ xl, const float* __restrict__ xr,
              const int* __restrict__ indptr, const int* __restrict__ srcs,
              const float* __restrict__ att, const float* __restrict__ conv_bias,
              const float* __restrict__ h_in, float* __restrict__ h_out) {
  int n = blockIdx.x;
  int wave = threadIdx.x >> 6;
  int lane = threadIdx.x & 63;
  int h = lane >> 4;
  int g = lane & 15;
  int ch = h * 128 + g * 8;

  __shared__ float s_scores[32];  // [slot][head]
  __shared__ float s_w[32];       // softmax weights per (slot, head)
  __shared__ float s_scale[4];    // per-head accumulator rescale for this chunk
  __shared__ float s_sum[4];      // running softmax denominator per head
  __shared__ float s_red[4][512]; // per-wave partial accumulators

  if (threadIdx.x < 4) s_sum[threadIdx.x] = 0.f;

  // per-lane fixed xr / att slice (registers, loaded once)
  float xr8[8], att8[8];
  {
    const float* xrp = xr + (size_t)n * 512 + ch;
    const float* atp = att + ch;
    *(float4*)&xr8[0] = *(const float4*)xrp;
    *(float4*)&xr8[4] = *(const float4*)(xrp + 4);
    *(float4*)&att8[0] = *(const float4*)atp;
    *(float4*)&att8[4] = *(const float4*)(atp + 4);
  }

  float acc[8];
#pragma unroll
  for (int j = 0; j < 8; ++j) acc[j] = 0.f;

  // wave-0 softmax running state (lanes 0..31: slot = lane>>2, head = lane&3)
  float m_run = -__builtin_inff();
  float s_run = 0.f;

  int beg = indptr[n];
  int deg = indptr[n + 1] - beg;
  int nchunk = (deg + 7) >> 3;

  for (int c = 0; c < nchunk; ++c) {
    int base = c * 8;
    // ---- score phase: this wave handles slots 2*wave, 2*wave+1
    float xl8[2][8];
#pragma unroll
    for (int t = 0; t < 2; ++t) {
      int slot = base + wave * 2 + t;
      float p = -__builtin_inff();
#pragma unroll
      for (int j = 0; j < 8; ++j) xl8[t][j] = 0.f;
      if (slot < deg) {
        int s = srcs[beg + slot];
        const float* xlp = xl + (size_t)s * 512 + ch;
        *(float4*)&xl8[t][0] = *(const float4*)xlp;
        *(float4*)&xl8[t][4] = *(const float4*)(xlp + 4);
        p = 0.f;
#pragma unroll
        for (int j = 0; j < 8; ++j) {
          float m = xl8[t][j] + xr8[j];
          float lk = fmaxf(m, 0.2f * m);  // leaky_relu, slope 0.2 < 1
          p = fmaf(att8[j], lk, p);
        }
      }
      // reduce partial dot over the 16-lane group
#pragma unroll
      for (int off = 1; off < 16; off <<= 1) p += __shfl_xor(p, off);
      if (g == 0) s_scores[(wave * 2 + t) * 4 + h] = p;
    }
    __syncthreads();

    // ---- softmax phase (wave 0, lanes 0..31): lane = slot*4 + head
    if (wave == 0 && lane < 32) {
      float val = s_scores[lane];
      float mx = val;
#pragma unroll
      for (int off = 4; off < 32; off <<= 1) mx = fmaxf(mx, __shfl_xor(mx, off));
      float m_new = fmaxf(m_run, mx);          // finite: chunk has >=1 valid edge
      float scl = expf(m_run - m_new);         // exp(-inf)=0 on first chunk
      float w = expf(val - m_new);             // val=-inf (pad) -> 0
      float ws = w;
#pragma unroll
      for (int off = 4; off < 32; off <<= 1) ws += __shfl_xor(ws, off);
      s_run = s_run * scl + ws;
      m_run = m_new;
      s_w[lane] = w;
      if (lane < 4) { s_scale[lane] = scl; s_sum[lane] = s_run; }
    }
    __syncthreads();

    // ---- aggregate phase: in-register, per-wave partial
    float scl = s_scale[h];
    float w0 = s_w[(wave * 2 + 0) * 4 + h];
    float w1 = s_w[(wave * 2 + 1) * 4 + h];
#pragma unroll
    for (int j = 0; j < 8; ++j) {
      float v = acc[j] * scl;
      v = fmaf(w0, xl8[0][j], v);
      v = fmaf(w1, xl8[1][j], v);
      acc[j] = v;
    }
  }

  // ---- cross-wave reduce + epilogue
  *(float4*)&s_red[wave][ch] = *(float4*)&acc[0];
  *(float4*)&s_red[wave][ch + 4] = *(float4*)&acc[4];
  __syncthreads();

  if (threadIdx.x < 128) {
    int cc = threadIdx.x;
    float v = 0.f;
#pragma unroll
    for (int hh = 0; hh < 4; ++hh) {
      float y = s_red[0][hh * 128 + cc] + s_red[1][hh * 128 + cc] +
                s_red[2][hh * 128 + cc] + s_red[3][hh * 128 + cc];
      v += y / fmaxf(s_sum[hh], 1e-16f);
    }
    v = v * 0.25f + conv_bias[cc] + h_in[(size_t)n * 128 + cc];
    h_out[(size_t)n * 128 + cc] = fmaxf(v, 0.f);
  }
}

// ---------------- final: score = clip(z2 @ p3_W + p3_b) ----------------

__global__ void __launch_bounds__(256)
predictor_final(const float* __restrict__ z2, const float* __restrict__ w3,
                const float* __restrict__ b3, float* __restrict__ out, int n) {
  int node = (blockIdx.x << 2) + (threadIdx.x >> 6);
  int lane = threadIdx.x & 63;
  if (node >= n) return;
  float v = z2[(size_t)node * 64 + lane] * w3[lane];
#pragma unroll
  for (int off = 32; off > 0; off >>= 1) v += __shfl_xor(v, off);
  if (lane == 0) {
    float s = v + b3[0];
    s = fminf(fmaxf(s, -15.f), 15.f);
    out[node] = s;
  }
}

// ---------------- launch ----------------

extern "C" void kernel_launch(void* const* d_in, const int* in_sizes, int n_in,
                              void* d_out, int out_size, void* d_ws, size_t ws_size,
                              hipStream_t stream) {
  const float* x     = (const float*)d_in[0];
  const int*   ei    = (const int*)d_in[1];
  const float* emb_W = (const float*)d_in[3];
  const float* emb_b = (const float*)d_in[4];
  const float* Wl    = (const float*)d_in[5];
  const float* bl    = (const float*)d_in[6];
  const float* Wr    = (const float*)d_in[7];
  const float* br    = (const float*)d_in[8];
  const float* att   = (const float*)d_in[9];
  const float* cbias = (const float*)d_in[10];
  const float* p1W   = (const float*)d_in[11];
  const float* p1b   = (const float*)d_in[12];
  const float* p2W   = (const float*)d_in[13];
  const float* p2b   = (const float*)d_in[14];
  const float* p3W   = (const float*)d_in[15];
  const float* p3b   = (const float*)d_in[16];
  float* out = (float*)d_out;

  char* ws = (char*)d_ws;
  size_t o = 0;
  float* h0 = (float*)(ws + o); o += (size_t)NN * 128 * 4;
  float* h1 = (float*)(ws + o); o += (size_t)NN * 128 * 4;
  float* xl = (float*)(ws + o); o += (size_t)NN * 512 * 4;
  float* xr = (float*)(ws + o); o += (size_t)NN * 512 * 4;
  int* indptr = (int*)(ws + o); o += (((size_t)(NN + 1) * 4) + 255) / 256 * 256;
  int* counts = (int*)(ws + o); o += (((size_t)NN * 4) + 255) / 256 * 256;
  int* srcs   = (int*)(ws + o); o += (size_t)NE * 4;

  const int* esrc = ei;
  const int* edst = ei + NE;

  // Build dst-CSR (same for all layers)
  hipMemsetAsync(counts, 0, (size_t)NN * 4, stream);
  hist_kernel<<<(NE + 255) / 256, 256, 0, stream>>>(edst, counts, NE);
  scan_kernel<<<1, 1024, 0, stream>>>(counts, indptr, NN);
  hipMemsetAsync(counts, 0, (size_t)NN * 4, stream);
  scatter_kernel<<<(NE + 255) / 256, 256, 0, stream>>>(esrc, edst, indptr, counts, srcs, NE);

  // Embedding: h0 = relu(x @ emb_W + emb_b)
  gemm_bias<1><<<dim3(128 / 64, (NN + 63) / 64), 256, 0, stream>>>(x, emb_W, emb_b, h0, NN, 64, 128);

  float* hc = h0;
  float* hn = h1;
  for (int l = 0; l < LAYERS; ++l) {
    gemm_bias<0><<<dim3(512 / 64, (NN + 63) / 64), 256, 0, stream>>>(
        hc, Wl + (size_t)l * 128 * 512, bl + (size_t)l * 512, xl, NN, 128, 512);
    gemm_bias<0><<<dim3(512 / 64, (NN + 63) / 64), 256, 0, stream>>>(
        hc, Wr + (size_t)l * 128 * 512, br + (size_t)l * 512, xr, NN, 128, 512);
    gat_aggregate<<<NN, 256, 0, stream>>>(xl, xr, indptr, srcs,
                                          att + (size_t)l * 512, cbias + (size_t)l * 128, hc, hn);
    float* t = hc; hc = hn; hn = t;
  }

  // Predictor MLP (reuse xl/xr as z1/z2)
  float* z1 = xl;
  float* z2 = xr;
  gemm_bias<1><<<dim3(128 / 64, (NN + 63) / 64), 256, 0, stream>>>(hc, p1W, p1b, z1, NN, 128, 128);
  gemm_bias<1><<<dim3(64 / 64, (NN + 63) / 64), 256, 0, stream>>>(z1, p2W, p2b, z2, NN, 128, 64);
  predictor_final<<<(NN + 3) / 4, 256, 0, stream>>>(z2, p3W, p3b, out, NN);
}

// Round 3
// 1225.523 us; speedup vs baseline: 1.4646x; 1.2605x over previous
//
#include <hip/hip_runtime.h>
#include <math.h>

#define NN 50000
#define NE 800000
#define F_IN 64
#define HID 128
#define HEADS 4
#define LAYERS 3

typedef __attribute__((ext_vector_type(8))) short bf16x8;
typedef __attribute__((ext_vector_type(8))) unsigned short ushort8;
typedef __attribute__((ext_vector_type(4))) float f32x4;

__device__ __forceinline__ float b2f(unsigned short u) {
  return __builtin_bit_cast(float, ((unsigned int)u) << 16);
}
__device__ __forceinline__ unsigned short f2bf(float f) {
  unsigned int u = __builtin_bit_cast(unsigned int, f);
  u = (u + 0x7FFFu + ((u >> 16) & 1u)) >> 16;
  return (unsigned short)u;
}

// ---------------- CSR build ----------------

__global__ void hist_kernel(const int* __restrict__ dst, int* __restrict__ counts, int E) {
  int e = blockIdx.x * blockDim.x + threadIdx.x;
  if (e < E) atomicAdd(&counts[dst[e]], 1);
}

__global__ void scan_kernel(const int* __restrict__ counts, int* __restrict__ indptr, int n) {
  __shared__ int buf[1024];
  __shared__ int carry_s;
  int tid = threadIdx.x;
  if (tid == 0) carry_s = 0;
  __syncthreads();
  for (int base = 0; base < n; base += 1024) {
    int v = (base + tid < n) ? counts[base + tid] : 0;
    buf[tid] = v;
    __syncthreads();
    for (int off = 1; off < 1024; off <<= 1) {
      int t = (tid >= off) ? buf[tid - off] : 0;
      __syncthreads();
      buf[tid] += t;
      __syncthreads();
    }
    int incl = buf[tid];
    int total = buf[1023];
    int carry = carry_s;
    if (base + tid < n) indptr[base + tid] = carry + incl - v;
    __syncthreads();
    if (tid == 0) carry_s = carry + total;
    __syncthreads();
  }
  if (tid == 0) indptr[n] = carry_s;
}

__global__ void scatter_kernel(const int* __restrict__ src, const int* __restrict__ dst,
                               const int* __restrict__ indptr, int* __restrict__ fill,
                               int* __restrict__ srcs, int E) {
  int e = blockIdx.x * blockDim.x + threadIdx.x;
  if (e < E) {
    int d = dst[e];
    int pos = atomicAdd(&fill[d], 1);
    srcs[indptr[d] + pos] = src[e];
  }
}

// ---------------- weight prep: split fp32 -> bf16 hi/lo, transpose [L][K][N] -> [L][N][K] ----------------

__global__ void prep_w(const float* __restrict__ W, unsigned short* __restrict__ Th,
                       unsigned short* __restrict__ Tl) {
  int id = blockIdx.x * 256 + threadIdx.x;   // < LAYERS*128*512
  int l = id >> 16;
  int rem = id & 65535;
  int k = rem >> 9;
  int n = rem & 511;
  float v = W[id];
  unsigned short h = f2bf(v);
  unsigned short lo = f2bf(v - b2f(h));
  int t = (l << 16) + n * 128 + k;
  Th[t] = h;
  Tl[t] = lo;
}

// ---------------- activation split: fp32 [M,128] -> bf16 hi/lo ----------------

__global__ void split_h(const float* __restrict__ H, unsigned short* __restrict__ Hh,
                        unsigned short* __restrict__ Hl) {
  int id = blockIdx.x * 256 + threadIdx.x;   // each handles 8 elems, total NN*128/8
  float x[8];
  *(float4*)&x[0] = ((const float4*)H)[id * 2 + 0];
  *(float4*)&x[4] = ((const float4*)H)[id * 2 + 1];
  ushort8 hv, lv;
#pragma unroll
  for (int j = 0; j < 8; ++j) {
    unsigned short h = f2bf(x[j]);
    hv[j] = h;
    lv[j] = f2bf(x[j] - b2f(h));
  }
  *(ushort8*)&Hh[(size_t)id * 8] = hv;
  *(ushort8*)&Hl[(size_t)id * 8] = lv;
}

// ---------------- MFMA GEMM (3-term bf16 split): C_bf16[M,512] = A[M,128] @ B[128,512] + bias ----------------
// A given as bf16 hi/lo [M][128]; B given transposed bf16 hi/lo [512][128].

__global__ void __launch_bounds__(256)
mfma_gemm(const unsigned short* __restrict__ Ah, const unsigned short* __restrict__ Al,
          const unsigned short* __restrict__ BTh, const unsigned short* __restrict__ BTl,
          const float* __restrict__ bias, unsigned short* __restrict__ C, int M) {
  __shared__ unsigned short sAh[128 * 40];
  __shared__ unsigned short sAl[128 * 40];
  __shared__ unsigned short sBh[128 * 40];
  __shared__ unsigned short sBl[128 * 40];

  int tid = threadIdx.x;
  int m0 = blockIdx.y * 128;
  int n0 = blockIdx.x * 128;
  int wv = tid >> 6, lane = tid & 63;
  int wr = wv >> 1, wc = wv & 1;

  f32x4 acc[4][4];
#pragma unroll
  for (int i = 0; i < 4; ++i)
#pragma unroll
    for (int j = 0; j < 4; ++j) acc[i][j] = (f32x4)0.f;

  for (int ks = 0; ks < 4; ++ks) {
#pragma unroll
    for (int j = 0; j < 2; ++j) {
      int id = tid + j * 256;
      int row = id >> 2, kg = id & 3;
      int koff = ks * 32 + kg * 8;
      int lidx = row * 40 + kg * 8;
      uint4 vah = make_uint4(0, 0, 0, 0), val = make_uint4(0, 0, 0, 0);
      int grow = m0 + row;
      if (grow < M) {
        vah = *(const uint4*)&Ah[(size_t)grow * 128 + koff];
        val = *(const uint4*)&Al[(size_t)grow * 128 + koff];
      }
      *(uint4*)&sAh[lidx] = vah;
      *(uint4*)&sAl[lidx] = val;
      uint4 vbh = *(const uint4*)&BTh[(size_t)(n0 + row) * 128 + koff];
      uint4 vbl = *(const uint4*)&BTl[(size_t)(n0 + row) * 128 + koff];
      *(uint4*)&sBh[lidx] = vbh;
      *(uint4*)&sBl[lidx] = vbl;
    }
    __syncthreads();

    bf16x8 fah[4], fal[4], fbh[4], fbl[4];
#pragma unroll
    for (int f = 0; f < 4; ++f) {
      int aoff = (wr * 64 + f * 16 + (lane & 15)) * 40 + (lane >> 4) * 8;
      fah[f] = *(const bf16x8*)&sAh[aoff];
      fal[f] = *(const bf16x8*)&sAl[aoff];
      int boff = (wc * 64 + f * 16 + (lane & 15)) * 40 + (lane >> 4) * 8;
      fbh[f] = *(const bf16x8*)&sBh[boff];
      fbl[f] = *(const bf16x8*)&sBl[boff];
    }
#pragma unroll
    for (int fm = 0; fm < 4; ++fm)
#pragma unroll
      for (int fn = 0; fn < 4; ++fn) {
        f32x4 c = acc[fm][fn];
        c = __builtin_amdgcn_mfma_f32_16x16x32_bf16(fal[fm], fbh[fn], c, 0, 0, 0);
        c = __builtin_amdgcn_mfma_f32_16x16x32_bf16(fah[fm], fbl[fn], c, 0, 0, 0);
        c = __builtin_amdgcn_mfma_f32_16x16x32_bf16(fah[fm], fbh[fn], c, 0, 0, 0);
        acc[fm][fn] = c;
      }
    __syncthreads();
  }

  float bv[4];
#pragma unroll
  for (int fn = 0; fn < 4; ++fn) bv[fn] = bias[n0 + wc * 64 + fn * 16 + (lane & 15)];
#pragma unroll
  for (int fm = 0; fm < 4; ++fm) {
    int rbase = m0 + wr * 64 + fm * 16 + (lane >> 4) * 4;
#pragma unroll
    for (int fn = 0; fn < 4; ++fn) {
      int col = n0 + wc * 64 + fn * 16 + (lane & 15);
#pragma unroll
      for (int r = 0; r < 4; ++r) {
        int row = rbase + r;
        if (row < M) C[(size_t)row * 512 + col] = f2bf(acc[fm][fn][r] + bv[fn]);
      }
    }
  }
}

// ---------------- fp32 tiled GEMM (emb / predictor): C = act(A @ B + bias) ----------------

template <int ACT>
__global__ void __launch_bounds__(256)
gemm_bias(const float* __restrict__ A, const float* __restrict__ B,
          const float* __restrict__ bias, float* __restrict__ C,
          int M, int K, int Nc) {
  __shared__ float As[16][68];
  __shared__ float Bs[16][68];
  int tid = threadIdx.x;
  int tx = tid & 15, ty = tid >> 4;
  int m0 = blockIdx.y * 64;
  int n0 = blockIdx.x * 64;

  int arow = tid >> 2;
  int acol = (tid & 3) * 4;
  int brow = tid >> 4;
  int bcol = (tid & 15) * 4;

  float acc[4][4];
#pragma unroll
  for (int i = 0; i < 4; ++i)
#pragma unroll
    for (int j = 0; j < 4; ++j) acc[i][j] = 0.f;

  for (int k0 = 0; k0 < K; k0 += 16) {
    float4 av = make_float4(0.f, 0.f, 0.f, 0.f);
    if (m0 + arow < M) av = *(const float4*)&A[(size_t)(m0 + arow) * K + k0 + acol];
    As[acol + 0][arow] = av.x;
    As[acol + 1][arow] = av.y;
    As[acol + 2][arow] = av.z;
    As[acol + 3][arow] = av.w;
    float4 bv = *(const float4*)&B[(size_t)(k0 + brow) * Nc + n0 + bcol];
    *(float4*)&Bs[brow][bcol] = bv;
    __syncthreads();
#pragma unroll
    for (int k = 0; k < 16; ++k) {
      float4 a = *(const float4*)&As[k][ty * 4];
      float4 b = *(const float4*)&Bs[k][tx * 4];
      acc[0][0] += a.x * b.x; acc[0][1] += a.x * b.y; acc[0][2] += a.x * b.z; acc[0][3] += a.x * b.w;
      acc[1][0] += a.y * b.x; acc[1][1] += a.y * b.y; acc[1][2] += a.y * b.z; acc[1][3] += a.y * b.w;
      acc[2][0] += a.z * b.x; acc[2][1] += a.z * b.y; acc[2][2] += a.z * b.z; acc[2][3] += a.z * b.w;
      acc[3][0] += a.w * b.x; acc[3][1] += a.w * b.y; acc[3][2] += a.w * b.z; acc[3][3] += a.w * b.w;
    }
    __syncthreads();
  }

#pragma unroll
  for (int i = 0; i < 4; ++i) {
    int row = m0 + ty * 4 + i;
    if (row < M) {
#pragma unroll
      for (int j = 0; j < 4; ++j) {
        int col = n0 + tx * 4 + j;
        float v = acc[i][j] + bias[col];
        if (ACT) v = fmaxf(v, 0.f);
        C[(size_t)row * Nc + col] = v;
      }
    }
  }
}

// ---------------- GATv2 edge phase: sync-free per-wave online softmax, bf16 gather ----------------
// lane = h*16+g, lane owns channels ch = h*128+g*8. Wave w handles edges {it*16 + w*4 + t}.
// Each wave keeps its own (m, s, acc); merged once at the end.

__global__ void __launch_bounds__(256)
gat_aggregate(const unsigned short* __restrict__ xl, const unsigned short* __restrict__ xr,
              const int* __restrict__ indptr, const int* __restrict__ srcs,
              const float* __restrict__ att, const float* __restrict__ conv_bias,
              const float* __restrict__ h_in, float* __restrict__ h_out) {
  int n = blockIdx.x;
  int w = threadIdx.x >> 6;
  int lane = threadIdx.x & 63;
  int h = lane >> 4;
  int g = lane & 15;
  int ch = h * 128 + g * 8;

  __shared__ float s_acc[4][528];   // wave-partial accumulators, ch2 = h*132+g*8
  __shared__ float s_m[4][4], s_s[4][4];
  __shared__ float s_coef[4][4];    // scale_w / den per (wave, head)

  // fixed per-lane xr / att slices
  float xr8[8], att8[8];
  {
    ushort8 xv = *(const ushort8*)&xr[(size_t)n * 512 + ch];
#pragma unroll
    for (int j = 0; j < 8; ++j) xr8[j] = b2f(xv[j]);
    const float* atp = att + ch;
    *(float4*)&att8[0] = *(const float4*)atp;
    *(float4*)&att8[4] = *(const float4*)(atp + 4);
  }

  float acc[8];
#pragma unroll
  for (int j = 0; j < 8; ++j) acc[j] = 0.f;
  float m_run = -__builtin_inff();
  float s_run = 0.f;

  int beg = indptr[n];
  int deg = indptr[n + 1] - beg;

  for (int slot0 = w * 4; slot0 < deg; slot0 += 16) {
    float p[4];
    float xf[4][8];
#pragma unroll
    for (int t = 0; t < 4; ++t) {
      int slot = slot0 + t;
      if (slot < deg) {
        int s = srcs[beg + slot];
        ushort8 xv = *(const ushort8*)&xl[(size_t)s * 512 + ch];
        float pp = 0.f;
#pragma unroll
        for (int j = 0; j < 8; ++j) {
          float xlf = b2f(xv[j]);
          xf[t][j] = xlf;
          float m = xlf + xr8[j];
          float lk = fmaxf(m, 0.2f * m);
          pp = fmaf(att8[j], lk, pp);
        }
        p[t] = pp;
      } else {
        p[t] = -__builtin_inff();
#pragma unroll
        for (int j = 0; j < 8; ++j) xf[t][j] = 0.f;
      }
    }
    // reduce scores over 16-lane group
#pragma unroll
    for (int t = 0; t < 4; ++t) {
#pragma unroll
      for (int off = 1; off < 16; off <<= 1) p[t] += __shfl_xor(p[t], off);
    }
    float mx = fmaxf(fmaxf(p[0], p[1]), fmaxf(p[2], p[3]));
    float m_new = fmaxf(m_run, mx);        // finite: slot0 < deg
    float scl = expf(m_run - m_new);       // first iter: exp(-inf)=0
    float w0 = expf(p[0] - m_new);
    float w1 = expf(p[1] - m_new);
    float w2 = expf(p[2] - m_new);
    float w3 = expf(p[3] - m_new);
    s_run = s_run * scl + ((w0 + w1) + (w2 + w3));
#pragma unroll
    for (int j = 0; j < 8; ++j) {
      float v = acc[j] * scl;
      v = fmaf(w0, xf[0][j], v);
      v = fmaf(w1, xf[1][j], v);
      v = fmaf(w2, xf[2][j], v);
      v = fmaf(w3, xf[3][j], v);
      acc[j] = v;
    }
    m_run = m_new;
  }

  // merge the 4 waves
  int ch2 = h * 132 + g * 8;
  *(float4*)&s_acc[w][ch2] = *(float4*)&acc[0];
  *(float4*)&s_acc[w][ch2 + 4] = *(float4*)&acc[4];
  if (g == 0) {
    s_m[w][h] = m_run;
    s_s[w][h] = s_run;
  }
  __syncthreads();

  if (threadIdx.x < 4) {
    int hh = threadIdx.x;
    float M = fmaxf(fmaxf(s_m[0][hh], s_m[1][hh]), fmaxf(s_m[2][hh], s_m[3][hh]));
    float sc[4];
    float den = 0.f;
#pragma unroll
    for (int ww = 0; ww < 4; ++ww) {
      float mw = s_m[ww][hh];
      float s = (mw > -1e37f) ? expf(mw - M) : 0.f;
      sc[ww] = s;
      den += s_s[ww][hh] * s;
    }
    float inv = 1.f / fmaxf(den, 1e-16f);
#pragma unroll
    for (int ww = 0; ww < 4; ++ww) s_coef[ww][hh] = sc[ww] * inv;
  }
  __syncthreads();

  if (threadIdx.x < 128) {
    int c = threadIdx.x;
    float v = 0.f;
#pragma unroll
    for (int hh = 0; hh < 4; ++hh) {
      int b = hh * 132 + c;
      v = fmaf(s_acc[0][b], s_coef[0][hh], v);
      v = fmaf(s_acc[1][b], s_coef[1][hh], v);
      v = fmaf(s_acc[2][b], s_coef[2][hh], v);
      v = fmaf(s_acc[3][b], s_coef[3][hh], v);
    }
    v = v * 0.25f + conv_bias[c] + h_in[(size_t)n * 128 + c];
    h_out[(size_t)n * 128 + c] = fmaxf(v, 0.f);
  }
}

// ---------------- final: score = clip(z2 @ p3_W + p3_b) ----------------

__global__ void __launch_bounds__(256)
predictor_final(const float* __restrict__ z2, const float* __restrict__ w3,
                const float* __restrict__ b3, float* __restrict__ out, int n) {
  int node = (blockIdx.x << 2) + (threadIdx.x >> 6);
  int lane = threadIdx.x & 63;
  if (node >= n) return;
  float v = z2[(size_t)node * 64 + lane] * w3[lane];
#pragma unroll
  for (int off = 32; off > 0; off >>= 1) v += __shfl_xor(v, off);
  if (lane == 0) {
    float s = v + b3[0];
    s = fminf(fmaxf(s, -15.f), 15.f);
    out[node] = s;
  }
}

// ---------------- launch ----------------

extern "C" void kernel_launch(void* const* d_in, const int* in_sizes, int n_in,
                              void* d_out, int out_size, void* d_ws, size_t ws_size,
                              hipStream_t stream) {
  const float* x     = (const float*)d_in[0];
  const int*   ei    = (const int*)d_in[1];
  const float* emb_W = (const float*)d_in[3];
  const float* emb_b = (const float*)d_in[4];
  const float* Wl    = (const float*)d_in[5];
  const float* bl    = (const float*)d_in[6];
  const float* Wr    = (const float*)d_in[7];
  const float* br    = (const float*)d_in[8];
  const float* att   = (const float*)d_in[9];
  const float* cbias = (const float*)d_in[10];
  const float* p1W   = (const float*)d_in[11];
  const float* p1b   = (const float*)d_in[12];
  const float* p2W   = (const float*)d_in[13];
  const float* p2b   = (const float*)d_in[14];
  const float* p3W   = (const float*)d_in[15];
  const float* p3b   = (const float*)d_in[16];
  float* out = (float*)d_out;

  char* ws = (char*)d_ws;
  size_t o = 0;
  float* h0 = (float*)(ws + o); o += (size_t)NN * 128 * 4;                 // 25.6 MB
  float* h1 = (float*)(ws + o); o += (size_t)NN * 128 * 4;                 // 25.6 MB
  unsigned short* h_hi = (unsigned short*)(ws + o); o += (size_t)NN * 128 * 2;  // 12.8 MB
  unsigned short* h_lo = (unsigned short*)(ws + o); o += (size_t)NN * 128 * 2;  // 12.8 MB
  unsigned short* xl_bf = (unsigned short*)(ws + o); o += (size_t)NN * 512 * 2; // 51.2 MB
  unsigned short* xr_bf = (unsigned short*)(ws + o); o += (size_t)NN * 512 * 2; // 51.2 MB
  unsigned short* WlT_hi = (unsigned short*)(ws + o); o += (size_t)LAYERS * 512 * 128 * 2;
  unsigned short* WlT_lo = (unsigned short*)(ws + o); o += (size_t)LAYERS * 512 * 128 * 2;
  unsigned short* WrT_hi = (unsigned short*)(ws + o); o += (size_t)LAYERS * 512 * 128 * 2;
  unsigned short* WrT_lo = (unsigned short*)(ws + o); o += (size_t)LAYERS * 512 * 128 * 2;
  int* indptr = (int*)(ws + o); o += (((size_t)(NN + 1) * 4) + 255) / 256 * 256;
  int* counts = (int*)(ws + o); o += (((size_t)NN * 4) + 255) / 256 * 256;
  int* srcs   = (int*)(ws + o); o += (size_t)NE * 4;

  const int* esrc = ei;
  const int* edst = ei + NE;

  // CSR build
  hipMemsetAsync(counts, 0, (size_t)NN * 4, stream);
  hist_kernel<<<(NE + 255) / 256, 256, 0, stream>>>(edst, counts, NE);
  scan_kernel<<<1, 1024, 0, stream>>>(counts, indptr, NN);
  hipMemsetAsync(counts, 0, (size_t)NN * 4, stream);
  scatter_kernel<<<(NE + 255) / 256, 256, 0, stream>>>(esrc, edst, indptr, counts, srcs, NE);

  // weight prep
  prep_w<<<(LAYERS * 128 * 512) / 256, 256, 0, stream>>>(Wl, WlT_hi, WlT_lo);
  prep_w<<<(LAYERS * 128 * 512) / 256, 256, 0, stream>>>(Wr, WrT_hi, WrT_lo);

  // embedding (fp32)
  gemm_bias<1><<<dim3(2, (NN + 63) / 64), 256, 0, stream>>>(x, emb_W, emb_b, h0, NN, 64, 128);

  float* hc = h0;
  float* hn = h1;
  for (int l = 0; l < LAYERS; ++l) {
    split_h<<<(NN * 128 / 8 + 255) / 256, 256, 0, stream>>>(hc, h_hi, h_lo);
    mfma_gemm<<<dim3(4, (NN + 127) / 128), 256, 0, stream>>>(
        h_hi, h_lo, WlT_hi + (size_t)l * 65536, WlT_lo + (size_t)l * 65536,
        bl + (size_t)l * 512, xl_bf, NN);
    mfma_gemm<<<dim3(4, (NN + 127) / 128), 256, 0, stream>>>(
        h_hi, h_lo, WrT_hi + (size_t)l * 65536, WrT_lo + (size_t)l * 65536,
        br + (size_t)l * 512, xr_bf, NN);
    gat_aggregate<<<NN, 256, 0, stream>>>(xl_bf, xr_bf, indptr, srcs,
                                          att + (size_t)l * 512, cbias + (size_t)l * 128, hc, hn);
    float* t = hc; hc = hn; hn = t;
  }

  // predictor (fp32), reuse xl/xr space
  float* z1 = (float*)xl_bf;
  float* z2 = (float*)xr_bf;
  gemm_bias<1><<<dim3(2, (NN + 63) / 64), 256, 0, stream>>>(hc, p1W, p1b, z1, NN, 128, 128);
  gemm_bias<1><<<dim3(1, (NN + 63) / 64), 256, 0, stream>>>(z1, p2W, p2b, z2, NN, 128, 64);
  predictor_final<<<(NN + 3) / 4, 256, 0, stream>>>(z2, p3W, p3b, out, NN);
}

// Round 4
// 961.351 us; speedup vs baseline: 1.8671x; 1.2748x over previous
//
#include <hip/hip_runtime.h>
#include <math.h>

#define NN 50000
#define NE 800000
#define F_IN 64
#define HID 128
#define HEADS 4
#define LAYERS 3

typedef __attribute__((ext_vector_type(8))) short bf16x8;
typedef __attribute__((ext_vector_type(8))) unsigned short ushort8;
typedef __attribute__((ext_vector_type(4))) float f32x4;
typedef __attribute__((ext_vector_type(4))) unsigned int u32x4;

__device__ __forceinline__ float b2f(unsigned short u) {
  return __builtin_bit_cast(float, ((unsigned int)u) << 16);
}
__device__ __forceinline__ unsigned short f2bf(float f) {
  unsigned int u = __builtin_bit_cast(unsigned int, f);
  u = (u + 0x7FFFu + ((u >> 16) & 1u)) >> 16;
  return (unsigned short)u;
}
__device__ __forceinline__ float bitf(unsigned int u) {
  return __builtin_bit_cast(float, u);
}

// ---------------- CSR build ----------------

__global__ void hist_kernel(const int* __restrict__ dst, int* __restrict__ counts, int E) {
  int e = blockIdx.x * blockDim.x + threadIdx.x;
  if (e < E) atomicAdd(&counts[dst[e]], 1);
}

__global__ void scan_kernel(const int* __restrict__ counts, int* __restrict__ indptr, int n) {
  __shared__ int buf[1024];
  __shared__ int carry_s;
  int tid = threadIdx.x;
  if (tid == 0) carry_s = 0;
  __syncthreads();
  for (int base = 0; base < n; base += 1024) {
    int v = (base + tid < n) ? counts[base + tid] : 0;
    buf[tid] = v;
    __syncthreads();
    for (int off = 1; off < 1024; off <<= 1) {
      int t = (tid >= off) ? buf[tid - off] : 0;
      __syncthreads();
      buf[tid] += t;
      __syncthreads();
    }
    int incl = buf[tid];
    int total = buf[1023];
    int carry = carry_s;
    if (base + tid < n) indptr[base + tid] = carry + incl - v;
    __syncthreads();
    if (tid == 0) carry_s = carry + total;
    __syncthreads();
  }
  if (tid == 0) indptr[n] = carry_s;
}

__global__ void scatter_kernel(const int* __restrict__ src, const int* __restrict__ dst,
                               const int* __restrict__ indptr, int* __restrict__ fill,
                               int* __restrict__ srcs, int E) {
  int e = blockIdx.x * blockDim.x + threadIdx.x;
  if (e < E) {
    int d = dst[e];
    int pos = atomicAdd(&fill[d], 1);
    srcs[indptr[d] + pos] = src[e];
  }
}

// ---------------- weight prep: split fp32 -> bf16 hi/lo, transpose [L][K][N] -> [L][N][K] ----------------

__global__ void prep_w(const float* __restrict__ W, unsigned short* __restrict__ Th,
                       unsigned short* __restrict__ Tl) {
  int id = blockIdx.x * 256 + threadIdx.x;
  int l = id >> 16;
  int rem = id & 65535;
  int k = rem >> 9;
  int n = rem & 511;
  float v = W[id];
  unsigned short h = f2bf(v);
  unsigned short lo = f2bf(v - b2f(h));
  int t = (l << 16) + n * 128 + k;
  Th[t] = h;
  Tl[t] = lo;
}

// ---------------- MFMA GEMM (3-term bf16 split): C_bf16[M,512] = A[M,128] @ B[128,512] + bias ----------------

__global__ void __launch_bounds__(256)
mfma_gemm(const unsigned short* __restrict__ Ah, const unsigned short* __restrict__ Al,
          const unsigned short* __restrict__ BTh, const unsigned short* __restrict__ BTl,
          const float* __restrict__ bias, unsigned short* __restrict__ C, int M) {
  __shared__ unsigned short sAh[128 * 40];
  __shared__ unsigned short sAl[128 * 40];
  __shared__ unsigned short sBh[128 * 40];
  __shared__ unsigned short sBl[128 * 40];

  // XCD-aware bijective swizzle: 4 consecutive wg (same M-tile, 4 N-tiles) per XCD chunk
  int nwg = gridDim.x;
  int f = blockIdx.x;
  int q = nwg >> 3, r = nwg & 7;
  int xcd = f & 7, idx = f >> 3;
  int wg = (xcd < r ? xcd * (q + 1) : r * (q + 1) + (xcd - r) * q) + idx;
  int m0 = (wg >> 2) * 128;
  int n0 = (wg & 3) * 128;

  int tid = threadIdx.x;
  int wv = tid >> 6, lane = tid & 63;
  int wr = wv >> 1, wc = wv & 1;

  f32x4 acc[4][4];
#pragma unroll
  for (int i = 0; i < 4; ++i)
#pragma unroll
    for (int j = 0; j < 4; ++j) acc[i][j] = (f32x4)0.f;

  for (int ks = 0; ks < 4; ++ks) {
#pragma unroll
    for (int j = 0; j < 2; ++j) {
      int id = tid + j * 256;
      int row = id >> 2, kg = id & 3;
      int koff = ks * 32 + kg * 8;
      int lidx = row * 40 + kg * 8;
      uint4 vah = make_uint4(0, 0, 0, 0), val = make_uint4(0, 0, 0, 0);
      int grow = m0 + row;
      if (grow < M) {
        vah = *(const uint4*)&Ah[(size_t)grow * 128 + koff];
        val = *(const uint4*)&Al[(size_t)grow * 128 + koff];
      }
      *(uint4*)&sAh[lidx] = vah;
      *(uint4*)&sAl[lidx] = val;
      uint4 vbh = *(const uint4*)&BTh[(size_t)(n0 + row) * 128 + koff];
      uint4 vbl = *(const uint4*)&BTl[(size_t)(n0 + row) * 128 + koff];
      *(uint4*)&sBh[lidx] = vbh;
      *(uint4*)&sBl[lidx] = vbl;
    }
    __syncthreads();

    bf16x8 fah[4], fal[4], fbh[4], fbl[4];
#pragma unroll
    for (int ff = 0; ff < 4; ++ff) {
      int aoff = (wr * 64 + ff * 16 + (lane & 15)) * 40 + (lane >> 4) * 8;
      fah[ff] = *(const bf16x8*)&sAh[aoff];
      fal[ff] = *(const bf16x8*)&sAl[aoff];
      int boff = (wc * 64 + ff * 16 + (lane & 15)) * 40 + (lane >> 4) * 8;
      fbh[ff] = *(const bf16x8*)&sBh[boff];
      fbl[ff] = *(const bf16x8*)&sBl[boff];
    }
#pragma unroll
    for (int fm = 0; fm < 4; ++fm)
#pragma unroll
      for (int fn = 0; fn < 4; ++fn) {
        f32x4 c = acc[fm][fn];
        c = __builtin_amdgcn_mfma_f32_16x16x32_bf16(fal[fm], fbh[fn], c, 0, 0, 0);
        c = __builtin_amdgcn_mfma_f32_16x16x32_bf16(fah[fm], fbl[fn], c, 0, 0, 0);
        c = __builtin_amdgcn_mfma_f32_16x16x32_bf16(fah[fm], fbh[fn], c, 0, 0, 0);
        acc[fm][fn] = c;
      }
    __syncthreads();
  }

  float bv[4];
#pragma unroll
  for (int fn = 0; fn < 4; ++fn) bv[fn] = bias[n0 + wc * 64 + fn * 16 + (lane & 15)];
#pragma unroll
  for (int fm = 0; fm < 4; ++fm) {
    int rbase = m0 + wr * 64 + fm * 16 + (lane >> 4) * 4;
#pragma unroll
    for (int fn = 0; fn < 4; ++fn) {
      int col = n0 + wc * 64 + fn * 16 + (lane & 15);
#pragma unroll
      for (int rr = 0; rr < 4; ++rr) {
        int row = rbase + rr;
        if (row < M) C[(size_t)row * 512 + col] = f2bf(acc[fm][fn][rr] + bv[fn]);
      }
    }
  }
}

// ---------------- fp32 tiled GEMM: C = act(A @ B + bias), optional bf16 hi/lo split outputs ----------------

template <int ACT, int SPLIT>
__global__ void __launch_bounds__(256)
gemm_bias(const float* __restrict__ A, const float* __restrict__ B,
          const float* __restrict__ bias, float* __restrict__ C,
          unsigned short* __restrict__ Ch, unsigned short* __restrict__ Cl,
          int M, int K, int Nc) {
  __shared__ float As[16][68];
  __shared__ float Bs[16][68];
  int tid = threadIdx.x;
  int tx = tid & 15, ty = tid >> 4;
  int m0 = blockIdx.y * 64;
  int n0 = blockIdx.x * 64;

  int arow = tid >> 2;
  int acol = (tid & 3) * 4;
  int brow = tid >> 4;
  int bcol = (tid & 15) * 4;

  float acc[4][4];
#pragma unroll
  for (int i = 0; i < 4; ++i)
#pragma unroll
    for (int j = 0; j < 4; ++j) acc[i][j] = 0.f;

  for (int k0 = 0; k0 < K; k0 += 16) {
    float4 av = make_float4(0.f, 0.f, 0.f, 0.f);
    if (m0 + arow < M) av = *(const float4*)&A[(size_t)(m0 + arow) * K + k0 + acol];
    As[acol + 0][arow] = av.x;
    As[acol + 1][arow] = av.y;
    As[acol + 2][arow] = av.z;
    As[acol + 3][arow] = av.w;
    float4 bv = *(const float4*)&B[(size_t)(k0 + brow) * Nc + n0 + bcol];
    *(float4*)&Bs[brow][bcol] = bv;
    __syncthreads();
#pragma unroll
    for (int k = 0; k < 16; ++k) {
      float4 a = *(const float4*)&As[k][ty * 4];
      float4 b = *(const float4*)&Bs[k][tx * 4];
      acc[0][0] += a.x * b.x; acc[0][1] += a.x * b.y; acc[0][2] += a.x * b.z; acc[0][3] += a.x * b.w;
      acc[1][0] += a.y * b.x; acc[1][1] += a.y * b.y; acc[1][2] += a.y * b.z; acc[1][3] += a.y * b.w;
      acc[2][0] += a.z * b.x; acc[2][1] += a.z * b.y; acc[2][2] += a.z * b.z; acc[2][3] += a.z * b.w;
      acc[3][0] += a.w * b.x; acc[3][1] += a.w * b.y; acc[3][2] += a.w * b.z; acc[3][3] += a.w * b.w;
    }
    __syncthreads();
  }

#pragma unroll
  for (int i = 0; i < 4; ++i) {
    int row = m0 + ty * 4 + i;
    if (row < M) {
#pragma unroll
      for (int j = 0; j < 4; ++j) {
        int col = n0 + tx * 4 + j;
        float v = acc[i][j] + bias[col];
        if (ACT) v = fmaxf(v, 0.f);
        C[(size_t)row * Nc + col] = v;
        if (SPLIT) {
          unsigned short hh = f2bf(v);
          Ch[(size_t)row * Nc + col] = hh;
          Cl[(size_t)row * Nc + col] = f2bf(v - b2f(hh));
        }
      }
    }
  }
}

// ---------------- GATv2 edge phase: 1 wave per node, no barriers ----------------
// lane = h*16+g, lane owns channels ch = h*128+g*8. 4 edges in flight per iter.
// leaky_relu(m)*att = (0.6*att)*m + (0.4*att)*|m|  (slope 0.2)

__global__ void __launch_bounds__(256)
gat_aggregate(const unsigned short* __restrict__ xl, const unsigned short* __restrict__ xr,
              const int* __restrict__ indptr, const int* __restrict__ srcs,
              const float* __restrict__ att, const float* __restrict__ conv_bias,
              const float* __restrict__ h_in, float* __restrict__ h_out,
              unsigned short* __restrict__ o_hi, unsigned short* __restrict__ o_lo,
              int write_split) {
  int node = blockIdx.x * 4 + (threadIdx.x >> 6);
  if (node >= NN) return;
  int lane = threadIdx.x & 63;
  int h = lane >> 4, g = lane & 15;
  int ch = h * 128 + g * 8;

  float a1[8], a2[8], xr8[8];
  {
    f32x4 t0 = *(const f32x4*)(att + ch);
    f32x4 t1 = *(const f32x4*)(att + ch + 4);
#pragma unroll
    for (int j = 0; j < 4; ++j) { a1[j] = 0.6f * t0[j]; a2[j] = 0.4f * t0[j]; }
#pragma unroll
    for (int j = 0; j < 4; ++j) { a1[4 + j] = 0.6f * t1[j]; a2[4 + j] = 0.4f * t1[j]; }
    u32x4 q = __builtin_nontemporal_load((const u32x4*)&xr[(size_t)node * 512 + ch]);
#pragma unroll
    for (int j = 0; j < 4; ++j) {
      xr8[2 * j] = bitf(q[j] << 16);
      xr8[2 * j + 1] = bitf(q[j] & 0xFFFF0000u);
    }
  }
  float base1 = 0.f;
#pragma unroll
  for (int j = 0; j < 8; ++j) base1 = fmaf(a1[j], xr8[j], base1);

  float acc[8];
#pragma unroll
  for (int j = 0; j < 8; ++j) acc[j] = 0.f;
  float m_run = -__builtin_inff();
  float s_run = 0.f;

  int beg = indptr[node];
  int deg = indptr[node + 1] - beg;

  for (int s0 = 0; s0 < deg; s0 += 4) {
    int sidx[4];
#pragma unroll
    for (int t = 0; t < 4; ++t) sidx[t] = (s0 + t < deg) ? srcs[beg + s0 + t] : -1;
    float xf[4][8], p[4];
#pragma unroll
    for (int t = 0; t < 4; ++t) {
      if (sidx[t] >= 0) {
        u32x4 q = *(const u32x4*)&xl[(size_t)sidx[t] * 512 + ch];
        float pp = base1;
#pragma unroll
        for (int j = 0; j < 4; ++j) {
          float e0 = bitf(q[j] << 16);
          float e1 = bitf(q[j] & 0xFFFF0000u);
          xf[t][2 * j] = e0;
          xf[t][2 * j + 1] = e1;
          float mm0 = e0 + xr8[2 * j];
          float mm1 = e1 + xr8[2 * j + 1];
          pp = fmaf(a1[2 * j], e0, pp);
          pp = fmaf(a2[2 * j], fabsf(mm0), pp);
          pp = fmaf(a1[2 * j + 1], e1, pp);
          pp = fmaf(a2[2 * j + 1], fabsf(mm1), pp);
        }
        p[t] = pp;
      } else {
        p[t] = -__builtin_inff();
#pragma unroll
        for (int j = 0; j < 8; ++j) xf[t][j] = 0.f;
      }
    }
#pragma unroll
    for (int t = 0; t < 4; ++t) {
#pragma unroll
      for (int off = 1; off < 16; off <<= 1) p[t] += __shfl_xor(p[t], off);
    }
    float mx = fmaxf(fmaxf(p[0], p[1]), fmaxf(p[2], p[3]));
    float m_new = fmaxf(m_run, mx);
    float scl = __expf(m_run - m_new);
    float w0 = __expf(p[0] - m_new);
    float w1 = __expf(p[1] - m_new);
    float w2 = __expf(p[2] - m_new);
    float w3 = __expf(p[3] - m_new);
    s_run = s_run * scl + ((w0 + w1) + (w2 + w3));
#pragma unroll
    for (int j = 0; j < 8; ++j) {
      float v = acc[j] * scl;
      v = fmaf(w0, xf[0][j], v);
      v = fmaf(w1, xf[1][j], v);
      v = fmaf(w2, xf[2][j], v);
      v = fmaf(w3, xf[3][j], v);
      acc[j] = v;
    }
    m_run = m_new;
  }

  // per-head normalize, then mean over heads in-wave
  float inv = 1.f / fmaxf(s_run, 1e-16f);
  float v[8];
#pragma unroll
  for (int j = 0; j < 8; ++j) v[j] = acc[j] * inv;
#pragma unroll
  for (int j = 0; j < 8; ++j) v[j] += __shfl_xor(v[j], 16);
#pragma unroll
  for (int j = 0; j < 8; ++j) v[j] += __shfl_xor(v[j], 32);

  if (h == 0) {
    int c0 = g * 8;
    const float* hip_ = h_in + (size_t)node * 128 + c0;
    f32x4 hi0 = __builtin_nontemporal_load((const f32x4*)hip_);
    f32x4 hi1 = __builtin_nontemporal_load((const f32x4*)(hip_ + 4));
    f32x4 cb0 = *(const f32x4*)(conv_bias + c0);
    f32x4 cb1 = *(const f32x4*)(conv_bias + c0 + 4);
    float rr[8];
#pragma unroll
    for (int j = 0; j < 4; ++j) rr[j] = fmaxf(fmaf(v[j], 0.25f, cb0[j] + hi0[j]), 0.f);
#pragma unroll
    for (int j = 0; j < 4; ++j) rr[4 + j] = fmaxf(fmaf(v[4 + j], 0.25f, cb1[j] + hi1[j]), 0.f);
    f32x4 o0, o1;
#pragma unroll
    for (int j = 0; j < 4; ++j) { o0[j] = rr[j]; o1[j] = rr[4 + j]; }
    float* hop = h_out + (size_t)node * 128 + c0;
    __builtin_nontemporal_store(o0, (f32x4*)hop);
    __builtin_nontemporal_store(o1, (f32x4*)(hop + 4));
    if (write_split) {
      ushort8 hv, lv;
#pragma unroll
      for (int j = 0; j < 8; ++j) {
        unsigned short hh = f2bf(rr[j]);
        hv[j] = hh;
        lv[j] = f2bf(rr[j] - b2f(hh));
      }
      __builtin_nontemporal_store(hv, (ushort8*)&o_hi[(size_t)node * 128 + c0]);
      __builtin_nontemporal_store(lv, (ushort8*)&o_lo[(size_t)node * 128 + c0]);
    }
  }
}

// ---------------- final: score = clip(z2 @ p3_W + p3_b) ----------------

__global__ void __launch_bounds__(256)
predictor_final(const float* __restrict__ z2, const float* __restrict__ w3,
                const float* __restrict__ b3, float* __restrict__ out, int n) {
  int node = (blockIdx.x << 2) + (threadIdx.x >> 6);
  int lane = threadIdx.x & 63;
  if (node >= n) return;
  float v = z2[(size_t)node * 64 + lane] * w3[lane];
#pragma unroll
  for (int off = 32; off > 0; off >>= 1) v += __shfl_xor(v, off);
  if (lane == 0) {
    float s = v + b3[0];
    s = fminf(fmaxf(s, -15.f), 15.f);
    out[node] = s;
  }
}

// ---------------- launch ----------------

extern "C" void kernel_launch(void* const* d_in, const int* in_sizes, int n_in,
                              void* d_out, int out_size, void* d_ws, size_t ws_size,
                              hipStream_t stream) {
  const float* x     = (const float*)d_in[0];
  const int*   ei    = (const int*)d_in[1];
  const float* emb_W = (const float*)d_in[3];
  const float* emb_b = (const float*)d_in[4];
  const float* Wl    = (const float*)d_in[5];
  const float* bl    = (const float*)d_in[6];
  const float* Wr    = (const float*)d_in[7];
  const float* br    = (const float*)d_in[8];
  const float* att   = (const float*)d_in[9];
  const float* cbias = (const float*)d_in[10];
  const float* p1W   = (const float*)d_in[11];
  const float* p1b   = (const float*)d_in[12];
  const float* p2W   = (const float*)d_in[13];
  const float* p2b   = (const float*)d_in[14];
  const float* p3W   = (const float*)d_in[15];
  const float* p3b   = (const float*)d_in[16];
  float* out = (float*)d_out;

  char* ws = (char*)d_ws;
  size_t o = 0;
  float* h0 = (float*)(ws + o); o += (size_t)NN * 128 * 4;
  float* h1 = (float*)(ws + o); o += (size_t)NN * 128 * 4;
  unsigned short* h_hi = (unsigned short*)(ws + o); o += (size_t)NN * 128 * 2;
  unsigned short* h_lo = (unsigned short*)(ws + o); o += (size_t)NN * 128 * 2;
  unsigned short* xl_bf = (unsigned short*)(ws + o); o += (size_t)NN * 512 * 2;
  unsigned short* xr_bf = (unsigned short*)(ws + o); o += (size_t)NN * 512 * 2;
  unsigned short* WlT_hi = (unsigned short*)(ws + o); o += (size_t)LAYERS * 512 * 128 * 2;
  unsigned short* WlT_lo = (unsigned short*)(ws + o); o += (size_t)LAYERS * 512 * 128 * 2;
  unsigned short* WrT_hi = (unsigned short*)(ws + o); o += (size_t)LAYERS * 512 * 128 * 2;
  unsigned short* WrT_lo = (unsigned short*)(ws + o); o += (size_t)LAYERS * 512 * 128 * 2;
  int* indptr = (int*)(ws + o); o += (((size_t)(NN + 1) * 4) + 255) / 256 * 256;
  int* counts = (int*)(ws + o); o += (((size_t)NN * 4) + 255) / 256 * 256;
  int* srcs   = (int*)(ws + o); o += (size_t)NE * 4;

  const int* esrc = ei;
  const int* edst = ei + NE;

  // CSR build
  hipMemsetAsync(counts, 0, (size_t)NN * 4, stream);
  hist_kernel<<<(NE + 255) / 256, 256, 0, stream>>>(edst, counts, NE);
  scan_kernel<<<1, 1024, 0, stream>>>(counts, indptr, NN);
  hipMemsetAsync(counts, 0, (size_t)NN * 4, stream);
  scatter_kernel<<<(NE + 255) / 256, 256, 0, stream>>>(esrc, edst, indptr, counts, srcs, NE);

  // weight prep
  prep_w<<<(LAYERS * 128 * 512) / 256, 256, 0, stream>>>(Wl, WlT_hi, WlT_lo);
  prep_w<<<(LAYERS * 128 * 512) / 256, 256, 0, stream>>>(Wr, WrT_hi, WrT_lo);

  // embedding (fp32) + bf16 hi/lo split fused
  gemm_bias<1, 1><<<dim3(2, (NN + 63) / 64), 256, 0, stream>>>(
      x, emb_W, emb_b, h0, h_hi, h_lo, NN, 64, 128);

  float* hc = h0;
  float* hn = h1;
  for (int l = 0; l < LAYERS; ++l) {
    mfma_gemm<<<4 * ((NN + 127) / 128), 256, 0, stream>>>(
        h_hi, h_lo, WlT_hi + (size_t)l * 65536, WlT_lo + (size_t)l * 65536,
        bl + (size_t)l * 512, xl_bf, NN);
    mfma_gemm<<<4 * ((NN + 127) / 128), 256, 0, stream>>>(
        h_hi, h_lo, WrT_hi + (size_t)l * 65536, WrT_lo + (size_t)l * 65536,
        br + (size_t)l * 512, xr_bf, NN);
    gat_aggregate<<<(NN + 3) / 4, 256, 0, stream>>>(
        xl_bf, xr_bf, indptr, srcs, att + (size_t)l * 512, cbias + (size_t)l * 128,
        hc, hn, h_hi, h_lo, (l < LAYERS - 1) ? 1 : 0);
    float* t = hc; hc = hn; hn = t;
  }

  // predictor (fp32), reuse xl/xr space
  float* z1 = (float*)xl_bf;
  float* z2 = (float*)xr_bf;
  gemm_bias<1, 0><<<dim3(2, (NN + 63) / 64), 256, 0, stream>>>(
      hc, p1W, p1b, z1, (unsigned short*)0, (unsigned short*)0, NN, 128, 128);
  gemm_bias<1, 0><<<dim3(1, (NN + 63) / 64), 256, 0, stream>>>(
      z1, p2W, p2b, z2, (unsigned short*)0, (unsigned short*)0, NN, 128, 64);
  predictor_final<<<(NN + 3) / 4, 256, 0, stream>>>(z2, p3W, p3b, out, NN);
}